// Round 7
// baseline (440.317 us; speedup 1.0000x reference)
//
#include <hip/hip_runtime.h>
#include <hip/hip_bf16.h>
#include <math.h>

#define B_    2
#define NPTS_ 32768
#define T_    32768
#define P_    512
#define C_    4
#define D_    768
#define M_    (B_ * T_)   // 65536

typedef __bf16 bf16_t;
typedef __bf16 bf16x8 __attribute__((ext_vector_type(8)));
typedef __bf16 bf16x4 __attribute__((ext_vector_type(4)));
typedef float  f32x4  __attribute__((ext_vector_type(4)));

__device__ inline void gload16(const void* g, void* l) {
  __builtin_amdgcn_global_load_lds(
      (const __attribute__((address_space(1))) void*)g,
      (__attribute__((address_space(3))) void*)l, 16, 0, 0);
}

__device__ inline float gelu_exact(float x) {
  return 0.5f * x * (1.0f + erff(x * 0.70710678118654752f));
}

// order-preserving float <-> uint map (for atomicMax on floats)
__device__ inline unsigned fmap(float x) {
  unsigned u = __float_as_uint(x);
  return (u & 0x80000000u) ? ~u : (u | 0x80000000u);
}
__device__ inline float funmap(unsigned u) {
  unsigned v = (u & 0x80000000u) ? (u & 0x7FFFFFFFu) : ~u;
  return __uint_as_float(v);
}

// ---- fused prep: 4x weight transpose + seg binary search + umax zero ----
__global__ __launch_bounds__(256) void prep_kernel(
    const int* __restrict__ off, int* __restrict__ seg, uint4* __restrict__ umax,
    const float* __restrict__ w1b, const float* __restrict__ w2a,
    const float* __restrict__ w2b,
    bf16_t* __restrict__ w1bT, bf16_t* __restrict__ w2aTT,
    bf16_t* __restrict__ w2aBT, bf16_t* __restrict__ w2bT) {
  __shared__ float tile[32][33];
  int bid = blockIdx.x, tid = threadIdx.x;
  if (bid < 2304) {
    const float* src; bf16_t* dst;
    int which = bid / 576, r = bid - which * 576;
    if (which == 0)      { src = w1b;             dst = w1bT;  }
    else if (which == 1) { src = w2a;             dst = w2aTT; }
    else if (which == 2) { src = w2a + D_ * D_;   dst = w2aBT; }
    else                 { src = w2b;             dst = w2bT;  }
    int n0 = (r % 24) * 32, k0 = (r / 24) * 32;
    int tx = tid & 31, ty = tid >> 5;
    #pragma unroll
    for (int i = 0; i < 4; ++i)
      tile[ty + 8 * i][tx] = src[(size_t)(k0 + ty + 8 * i) * D_ + n0 + tx];
    __syncthreads();
    #pragma unroll
    for (int i = 0; i < 4; ++i)
      dst[(size_t)(n0 + ty + 8 * i) * D_ + k0 + tx] = (bf16_t)tile[tx][ty + 8 * i];
  } else if (bid < 2432) {
    int t = (bid - 2304) * 256 + tid;
    int lo = 0, hi = P_;
    while (lo < hi) {
      int mid = (lo + hi) >> 1;
      if (off[mid + 1] <= t) lo = mid + 1; else hi = mid;
    }
    seg[t] = lo;
  } else {
    umax[(size_t)(bid - 2432) * 256 + tid] = make_uint4(0, 0, 0, 0);
  }
}

// ---------------- unmap ymax -> bf16 y ---------------------------------
__global__ __launch_bounds__(256) void yconv_kernel(
    const uint4* __restrict__ ymax, bf16_t* __restrict__ y) {
  int t = blockIdx.x * 256 + threadIdx.x;   // 196608 total
  uint4 u = ymax[t];
  bf16x4 o;
  o[0] = (bf16_t)funmap(u.x); o[1] = (bf16_t)funmap(u.y);
  o[2] = (bf16_t)funmap(u.z); o[3] = (bf16_t)funmap(u.w);
  *(bf16x4*)(y + (size_t)t * 4) = o;
}

// ---------------- unmap rmax + pos_embed -> out fp32 -------------------
__global__ __launch_bounds__(256) void final2_kernel(
    const uint4* __restrict__ rmax, const float4* __restrict__ pe,
    float4* __restrict__ out) {
  int t = blockIdx.x * 256 + threadIdx.x;   // 196608 total
  int row = t / 192, col = t % 192;         // 768/4 = 192
  uint4 u = rmax[t];
  float4 p = pe[(row & (P_ - 1)) * 192 + col];
  float4 o;
  o.x = funmap(u.x) + p.x; o.y = funmap(u.y) + p.y;
  o.z = funmap(u.z) + p.z; o.w = funmap(u.w) + p.w;
  out[t] = o;
}

// -------- fused: gather latent -> @w1a + b1a -> LN(1e-6) -> gelu -> bf16
__global__ __launch_bounds__(256) void embed_kernel(
    const float4* __restrict__ latent4, const int* __restrict__ pidx,
    const float* __restrict__ w1a, const float* __restrict__ b1a,
    bf16_t* __restrict__ act1) {
  int wid = threadIdx.x >> 6, lane = threadIdx.x & 63;
  int m = blockIdx.x * 4 + wid;
  int b = m >> 15, t = m & (T_ - 1);
  float4 x = latent4[(size_t)b * NPTS_ + pidx[t]];
  int d8 = lane * 8, d4 = 512 + lane * 4;
  float v[12];
  {
    float4 a0 = *(const float4*)(b1a + d8);
    float4 a1 = *(const float4*)(b1a + d8 + 4);
    float4 a2 = *(const float4*)(b1a + d4);
    v[0]=a0.x; v[1]=a0.y; v[2]=a0.z; v[3]=a0.w;
    v[4]=a1.x; v[5]=a1.y; v[6]=a1.z; v[7]=a1.w;
    v[8]=a2.x; v[9]=a2.y; v[10]=a2.z; v[11]=a2.w;
  }
  float xk[4] = {x.x, x.y, x.z, x.w};
  #pragma unroll
  for (int k = 0; k < 4; ++k) {
    const float* w = w1a + k * D_;
    float4 w0 = *(const float4*)(w + d8);
    float4 w1 = *(const float4*)(w + d8 + 4);
    float4 w2 = *(const float4*)(w + d4);
    float f = xk[k];
    v[0] += f*w0.x; v[1] += f*w0.y; v[2] += f*w0.z; v[3] += f*w0.w;
    v[4] += f*w1.x; v[5] += f*w1.y; v[6] += f*w1.z; v[7] += f*w1.w;
    v[8] += f*w2.x; v[9] += f*w2.y; v[10]+= f*w2.z; v[11]+= f*w2.w;
  }
  float sum = 0.f, sq = 0.f;
  #pragma unroll
  for (int j = 0; j < 12; ++j) { sum += v[j]; sq += v[j]*v[j]; }
  #pragma unroll
  for (int o = 32; o > 0; o >>= 1) { sum += __shfl_xor(sum, o); sq += __shfl_xor(sq, o); }
  float mu = sum * (1.0f / D_);
  float rstd = rsqrtf(sq * (1.0f / D_) - mu * mu + 1e-6f);
  bf16x8 o8; bf16x4 o4;
  #pragma unroll
  for (int j = 0; j < 8; ++j) o8[j] = (bf16_t)gelu_exact((v[j] - mu) * rstd);
  #pragma unroll
  for (int j = 0; j < 4; ++j) o4[j] = (bf16_t)gelu_exact((v[8 + j] - mu) * rstd);
  size_t base = (size_t)m * D_;
  *(bf16x8*)(act1 + base + d8) = o8;
  *(bf16x4*)(act1 + base + d4) = o4;
}

// ---- h2 = h2partial + z[seg]; LN(1e-5, g2, beta2) + gelu -> bf16 -------
__global__ __launch_bounds__(256) void ln2_kernel(
    const bf16_t* __restrict__ h2pre, const float* __restrict__ z,
    const int* __restrict__ seg, const float* __restrict__ g2,
    const float* __restrict__ beta2, bf16_t* __restrict__ act2) {
  int wid = threadIdx.x >> 6, lane = threadIdx.x & 63;
  int m = blockIdx.x * 4 + wid;
  int b = m >> 15, t = m & (T_ - 1);
  int d8 = lane * 8, d4 = 512 + lane * 4;
  size_t base = (size_t)m * D_;
  const float* zrow = z + (size_t)((b << 9) + seg[t]) * D_;
  bf16x8 i8 = *(const bf16x8*)(h2pre + base + d8);
  bf16x4 i4 = *(const bf16x4*)(h2pre + base + d4);
  float4 z0 = *(const float4*)(zrow + d8);
  float4 z1 = *(const float4*)(zrow + d8 + 4);
  float4 z2 = *(const float4*)(zrow + d4);
  float v[12];
  #pragma unroll
  for (int j = 0; j < 8; ++j) v[j] = (float)i8[j];
  #pragma unroll
  for (int j = 0; j < 4; ++j) v[8 + j] = (float)i4[j];
  v[0]+=z0.x; v[1]+=z0.y; v[2]+=z0.z; v[3]+=z0.w;
  v[4]+=z1.x; v[5]+=z1.y; v[6]+=z1.z; v[7]+=z1.w;
  v[8]+=z2.x; v[9]+=z2.y; v[10]+=z2.z; v[11]+=z2.w;
  float sum = 0.f, sq = 0.f;
  #pragma unroll
  for (int j = 0; j < 12; ++j) { sum += v[j]; sq += v[j]*v[j]; }
  #pragma unroll
  for (int o = 32; o > 0; o >>= 1) { sum += __shfl_xor(sum, o); sq += __shfl_xor(sq, o); }
  float mu = sum * (1.0f / D_);
  float rstd = rsqrtf(sq * (1.0f / D_) - mu * mu + 1e-5f);
  float4 ga = *(const float4*)(g2 + d8);
  float4 gb = *(const float4*)(g2 + d8 + 4);
  float4 gc = *(const float4*)(g2 + d4);
  float4 ba = *(const float4*)(beta2 + d8);
  float4 bb = *(const float4*)(beta2 + d8 + 4);
  float4 bc = *(const float4*)(beta2 + d4);
  float g[12] = {ga.x,ga.y,ga.z,ga.w, gb.x,gb.y,gb.z,gb.w, gc.x,gc.y,gc.z,gc.w};
  float be[12]= {ba.x,ba.y,ba.z,ba.w, bb.x,bb.y,bb.z,bb.w, bc.x,bc.y,bc.z,bc.w};
  bf16x8 o8; bf16x4 o4;
  #pragma unroll
  for (int j = 0; j < 8; ++j) o8[j] = (bf16_t)gelu_exact((v[j] - mu) * rstd * g[j] + be[j]);
  #pragma unroll
  for (int j = 0; j < 4; ++j) o4[j] = (bf16_t)gelu_exact((v[8+j] - mu) * rstd * g[8+j] + be[8+j]);
  *(bf16x8*)(act2 + base + d8) = o8;
  *(bf16x4*)(act2 + base + d4) = o4;
}

// ===== 256x256 4-phase MFMA GEMM, SWAPPED operands for coalesced C ======
// mfma(B_frag, A_frag): thread (lr,hi) reg r holds C[m = lr][n = hi*4+r]
// -> fp32 C: 16B/lane stores (full 64B sectors); bf16: 8B/lane, jb-adjacent.
#define STAGE_A(P2, KTG)                                                     \
  { _Pragma("unroll")                                                        \
    for (int h = 0; h < 2; ++h) {                                            \
      _Pragma("unroll")                                                      \
      for (int ps = 0; ps < 2; ++ps) {                                       \
        int c = ps * 512 + wid * 64 + lane;                                  \
        int rw = c >> 3;                                                     \
        int cs = (c & 7) ^ (rw & 7);                                         \
        gload16(A + (size_t)(m0 + h * 128 + rw) * 768 + (KTG) + cs * 8,      \
                lds + (P2) * 65536 + h * 16384 + ps * 8192 + wid * 1024);    \
      } } }

#define STAGE_B(P2, KTG)                                                     \
  { _Pragma("unroll")                                                        \
    for (int h = 0; h < 2; ++h) {                                            \
      _Pragma("unroll")                                                      \
      for (int ps = 0; ps < 2; ++ps) {                                       \
        int c = ps * 512 + wid * 64 + lane;                                  \
        int rw = c >> 3;                                                     \
        int cs = (c & 7) ^ (rw & 7);                                         \
        gload16(BT + (size_t)(n0 + h * 128 + rw) * 768 + (KTG) + cs * 8,     \
                lds + (P2) * 65536 + 32768 + h * 16384 + ps * 8192 + wid * 1024); \
      } } }

#define READ_AF0(BASE)                                                       \
  { _Pragma("unroll")                                                        \
    for (int i = 0; i < 4; ++i) {                                            \
      _Pragma("unroll")                                                      \
      for (int s = 0; s < 2; ++s) {                                          \
        int row = i * 16 + lr;                                               \
        int ch = (s * 4 + hi) ^ cx;                                          \
        af0[i][s] = *(const bf16x8*)((BASE) + wm * 16384 + row * 128 + ch * 16); \
      } } }

#define READ_BF0(BASE)                                                       \
  { _Pragma("unroll")                                                        \
    for (int jb = 0; jb < 2; ++jb) {                                         \
      _Pragma("unroll")                                                      \
      for (int s = 0; s < 2; ++s) {                                          \
        int nrow = wn * 64 + jb * 16 + lr;                                   \
        int ch = (s * 4 + hi) ^ cx;                                          \
        bf0[jb][s] = *(const bf16x8*)((BASE) + 32768 + (nrow >> 7) * 16384 + \
                                      (nrow & 127) * 128 + ch * 16);         \
      } } }

template <bool HASBIAS, bool SEGMAX, typename OutT>
__global__ __launch_bounds__(512, 1) void gemm256_kernel(
    const bf16_t* __restrict__ A, const bf16_t* __restrict__ BT,
    const float* __restrict__ bias, OutT* __restrict__ C,
    const int* __restrict__ seg, unsigned* __restrict__ gmax) {
  constexpr int NT = 12;                 // 768 / 64
  __shared__ __align__(16) char lds[131072];
  __shared__ int segm[256];
  int tid = threadIdx.x;
  int wid = tid >> 6, lane = tid & 63;
  int lr = lane & 15, hi = lane >> 4;
  int wm = wid >> 2, wn = wid & 3;

  int gx = gridDim.x;                    // 3
  int nb = gx * gridDim.y;
  int bid = blockIdx.y * gx + blockIdx.x;
  int w = ((nb & 7) == 0) ? ((bid & 7) * (nb >> 3) + (bid >> 3)) : bid;
  int bx = w % gx, by = w / gx;
  int n0 = bx * 256, m0 = by * 256;

  if (SEGMAX) { if (tid < 256) segm[tid] = seg[(m0 + tid) & (T_ - 1)]; }

  f32x4 acc[8][4] = {};
  bf16x8 af0[4][2], af1[4][2], bf0[2][2], bf1[2][2];
  int cx = lr & 7;

  // prologue: stage K-tiles 0 and 1; gate tile 0; pre-read af0/bf0 of tile 0
  STAGE_A(0, 0); STAGE_B(0, 0);
  STAGE_A(1, 64); STAGE_B(1, 64);
  asm volatile("s_waitcnt vmcnt(8)" ::: "memory");
  __builtin_amdgcn_s_barrier();
  READ_AF0(lds); READ_BF0(lds);

  for (int j = 0; j < NT; ++j) {
    const char* base  = lds + (j & 1) * 65536;
    const char* baseN = lds + ((j & 1) ^ 1) * 65536;

    // ---- P0: read af1(j); MFMA Q00 ----
    #pragma unroll
    for (int i = 0; i < 4; ++i)
      #pragma unroll
      for (int s = 0; s < 2; ++s) {
        int row = 64 + i * 16 + lr;
        int ch = (s * 4 + hi) ^ cx;
        af1[i][s] = *(const bf16x8*)(base + wm * 16384 + row * 128 + ch * 16);
      }
    __builtin_amdgcn_s_setprio(1);
    #pragma unroll
    for (int i = 0; i < 4; ++i)
      #pragma unroll
      for (int jb = 0; jb < 2; ++jb)
        #pragma unroll
        for (int s = 0; s < 2; ++s)
          acc[i][jb] = __builtin_amdgcn_mfma_f32_16x16x32_bf16(bf0[jb][s], af0[i][s], acc[i][jb], 0, 0, 0);
    __builtin_amdgcn_s_setprio(0);
    __builtin_amdgcn_s_barrier();

    // ---- P1: read bf1(j); MFMA Q10 ----
    #pragma unroll
    for (int jb = 0; jb < 2; ++jb)
      #pragma unroll
      for (int s = 0; s < 2; ++s) {
        int nrow = wn * 64 + 32 + jb * 16 + lr;
        int ch = (s * 4 + hi) ^ cx;
        bf1[jb][s] = *(const bf16x8*)(base + 32768 + (nrow >> 7) * 16384 +
                                      (nrow & 127) * 128 + ch * 16);
      }
    __builtin_amdgcn_s_setprio(1);
    #pragma unroll
    for (int i = 0; i < 4; ++i)
      #pragma unroll
      for (int jb = 0; jb < 2; ++jb)
        #pragma unroll
        for (int s = 0; s < 2; ++s)
          acc[4 + i][jb] = __builtin_amdgcn_mfma_f32_16x16x32_bf16(bf0[jb][s], af1[i][s], acc[4 + i][jb], 0, 0, 0);
    __builtin_amdgcn_s_setprio(0);
    __builtin_amdgcn_s_barrier();

    // ---- P2: stage A(j+2); MFMA Q01 ----
    if (j + 2 < NT) STAGE_A(j & 1, (j + 2) * 64);
    __builtin_amdgcn_s_setprio(1);
    #pragma unroll
    for (int i = 0; i < 4; ++i)
      #pragma unroll
      for (int jb = 0; jb < 2; ++jb)
        #pragma unroll
        for (int s = 0; s < 2; ++s)
          acc[i][2 + jb] = __builtin_amdgcn_mfma_f32_16x16x32_bf16(bf1[jb][s], af0[i][s], acc[i][2 + jb], 0, 0, 0);
    __builtin_amdgcn_s_setprio(0);

    // ---- P3: gate tile j+1; read af0/bf0(j+1); stage B(j+2); MFMA Q11 ----
    if (j + 1 < NT) {
      if (j + 2 < NT) asm volatile("s_waitcnt vmcnt(4)" ::: "memory");
      else            asm volatile("s_waitcnt vmcnt(0)" ::: "memory");
      __builtin_amdgcn_s_barrier();   // all waves: tile j+1 landed, B(j) dead
      READ_AF0(baseN); READ_BF0(baseN);
      if (j + 2 < NT) STAGE_B(j & 1, (j + 2) * 64);
    }
    __builtin_amdgcn_s_setprio(1);
    #pragma unroll
    for (int i = 0; i < 4; ++i)
      #pragma unroll
      for (int jb = 0; jb < 2; ++jb)
        #pragma unroll
        for (int s = 0; s < 2; ++s)
          acc[4 + i][2 + jb] = __builtin_amdgcn_mfma_f32_16x16x32_bf16(bf1[jb][s], af1[i][s], acc[4 + i][2 + jb], 0, 0, 0);
    __builtin_amdgcn_s_setprio(0);
    __builtin_amdgcn_s_barrier();
  }

  // ---- epilogue ----
  unsigned* smax = reinterpret_cast<unsigned*>(lds);
  int sb = 0, zb = 0;
  if (SEGMAX) {
    sb = segm[0];
    zb = (m0 >> 15) << 9;                // batch * 512
    for (int q = tid; q < 16 * 256; q += 512) smax[q] = 0u;
    __syncthreads();
  }

  f32x4 bvv[4];
  #pragma unroll
  for (int jb = 0; jb < 4; ++jb) {
    if (HASBIAS) {
      const float* bp = bias + n0 + wn * 64 + jb * 16 + hi * 4;
      bvv[jb][0] = bp[0]; bvv[jb][1] = bp[1]; bvv[jb][2] = bp[2]; bvv[jb][3] = bp[3];
    } else {
      bvv[jb][0] = bvv[jb][1] = bvv[jb][2] = bvv[jb][3] = 0.f;
    }
  }

  // coalesced C store: thread holds 4 consecutive n at fixed row m
  #pragma unroll
  for (int i = 0; i < 8; ++i) {
    size_t ro = (size_t)(m0 + wm * 128 + i * 16 + lr) * 768 + (n0 + wn * 64 + hi * 4);
    #pragma unroll
    for (int jb = 0; jb < 4; ++jb) {
      f32x4 v = acc[i][jb] + bvv[jb];
      if constexpr (sizeof(OutT) == 4) {
        *reinterpret_cast<f32x4*>(C + ro + jb * 16) = v;
      } else {
        bf16x4 o;
        #pragma unroll
        for (int r = 0; r < 4; ++r) o[r] = (bf16_t)v[r];
        *reinterpret_cast<bf16x4*>(C + ro + jb * 16) = o;
      }
    }
  }

  if (SEGMAX) {
    int lrow = wm * 128 + lr;
    #pragma unroll
    for (int jb = 0; jb < 4; ++jb) {
      int nl = wn * 64 + jb * 16 + hi * 4;
      f32x4 run = acc[0][jb] + bvv[jb];
      int ps = segm[lrow];
      #pragma unroll
      for (int i = 1; i < 8; ++i) {
        int cs2 = segm[lrow + i * 16];
        f32x4 v = acc[i][jb] + bvv[jb];
        if (cs2 != ps) {
          #pragma unroll
          for (int r = 0; r < 4; ++r)
            atomicMax(&smax[(ps - sb) * 256 + nl + r], fmap(run[r]));
          run = v; ps = cs2;
        } else {
          #pragma unroll
          for (int r = 0; r < 4; ++r) run[r] = fmaxf(run[r], v[r]);
        }
      }
      #pragma unroll
      for (int r = 0; r < 4; ++r)
        atomicMax(&smax[(ps - sb) * 256 + nl + r], fmap(run[r]));
    }
    __syncthreads();
    int nseg = segm[255] - sb + 1;
    int mlo = m0 & (T_ - 1);
    bool strad_lo = (mlo != 0) && (seg[(mlo - 1)] == sb);
    bool strad_hi = (mlo + 256 < T_) && (seg[(mlo + 256)] == segm[255]);
    for (int q = tid; q < nseg * 256; q += 512) {
      int sl = q >> 8, nl2 = q & 255;
      unsigned val = smax[q];
      unsigned* dst = &gmax[(size_t)(zb + sb + sl) * 768 + n0 + nl2];
      bool bdry = (sl == 0 && strad_lo) || (sl == nseg - 1 && strad_hi);
      if (bdry) atomicMax(dst, val);
      else      *dst = val;               // exclusive owner of this segment
    }
  }
}

extern "C" void kernel_launch(void* const* d_in, const int* in_sizes, int n_in,
                              void* d_out, int out_size, void* d_ws, size_t ws_size,
                              hipStream_t stream) {
  const float* latent       = (const float*)d_in[0];
  const int*   patch_index  = (const int*)d_in[1];
  const int*   patch_offset = (const int*)d_in[2];
  const float* pos_embed    = (const float*)d_in[3];
  const float* w1a  = (const float*)d_in[4];
  const float* b1a  = (const float*)d_in[5];
  const float* w1b  = (const float*)d_in[6];
  const float* b1b  = (const float*)d_in[7];
  const float* w2a  = (const float*)d_in[8];
  const float* b2a  = (const float*)d_in[9];
  const float* g2   = (const float*)d_in[10];
  const float* beta2= (const float*)d_in[11];
  const float* w2b  = (const float*)d_in[12];
  const float* b2b  = (const float*)d_in[13];

  float* out_f   = (float*)d_out;
  float* raw_out = out_f + (size_t)B_ * P_ * D_;

  char* ws = (char*)d_ws;
  size_t off = 0;
  auto take = [&](size_t bytes) {
    off = (off + 255) & ~(size_t)255;
    char* p = ws + off;
    off += bytes;
    return p;
  };
  int*      seg   = (int*)     take((size_t)T_ * 4);
  bf16_t*   w1bT  = (bf16_t*)  take((size_t)D_ * D_ * 2);
  bf16_t*   w2aTT = (bf16_t*)  take((size_t)D_ * D_ * 2);
  bf16_t*   w2aBT = (bf16_t*)  take((size_t)D_ * D_ * 2);
  bf16_t*   w2bT  = (bf16_t*)  take((size_t)D_ * D_ * 2);
  bf16_t*   ybuf  = (bf16_t*)  take((size_t)B_ * P_ * D_ * 2);
  float*    zbuf  = (float*)   take((size_t)B_ * P_ * D_ * 4);
  unsigned* umax  = (unsigned*)take((size_t)2 * B_ * P_ * D_ * 4);  // ymax|rmax
  unsigned* ymax  = umax;
  unsigned* rmax  = umax + (size_t)B_ * P_ * D_;
  bf16_t*   bufY  = (bf16_t*)  take((size_t)M_ * D_ * 2);
  size_t needX = (size_t)M_ * D_ * 2;
  size_t offX  = (off + 255) & ~(size_t)255;
  bf16_t* bufX;
  if (offX + needX <= ws_size) {
    bufX = (bf16_t*)take(needX);
  } else {
    bufX = (bf16_t*)raw_out;  // dead before gemm4 overwrites with real raw
  }

  // fused prep: 4 weight transposes + seg + umax zero
  prep_kernel<<<3968, 256, 0, stream>>>(patch_offset, seg, (uint4*)umax,
                                        w1b, w2a, w2b, w1bT, w2aTT, w2aBT, w2bT);

  // act1 = gelu(LN(latent[pidx] @ w1a + b1a))
  embed_kernel<<<M_ / 4, 256, 0, stream>>>((const float4*)latent, patch_index, w1a, b1a, bufX);

  // h = act1 @ w1b + b1b; fused y = segmax(h) -> ymax
  gemm256_kernel<true, true, bf16_t><<<dim3(3, M_/256), 512, 0, stream>>>(
      bufX, w1bT, b1b, bufY, seg, ymax);

  // y bf16
  yconv_kernel<<<(B_ * P_ * D_) / (4 * 256), 256, 0, stream>>>((const uint4*)ymax, ybuf);

  // z = y @ w2a_top + b2a   (1024 x 768 x 768, fp32 out)
  gemm256_kernel<true, false, float><<<dim3(3, (B_*P_)/256), 512, 0, stream>>>(
      ybuf, w2aTT, b2a, zbuf, nullptr, nullptr);

  // h2partial = h @ w2a_bot   (no bias; z added in ln2)
  gemm256_kernel<false, false, bf16_t><<<dim3(3, M_/256), 512, 0, stream>>>(
      bufY, w2aBT, nullptr, bufX, nullptr, nullptr);

  // act2 = gelu(LN(h2partial + z[seg]) * g2 + beta2)
  ln2_kernel<<<M_ / 4, 256, 0, stream>>>(bufX, zbuf, seg, g2, beta2, bufY);

  // raw = act2 @ w2b + b2b (fp32 -> d_out); fused segmax -> rmax
  gemm256_kernel<true, true, float><<<dim3(3, M_/256), 512, 0, stream>>>(
      bufY, w2bT, b2b, raw_out, seg, rmax);

  // out = unmap(rmax) + pos_embed
  final2_kernel<<<(B_ * P_ * D_) / (4 * 256), 256, 0, stream>>>(
      (const uint4*)rmax, (const float4*)pos_embed, (float4*)out_f);
}